// Round 3
// baseline (2379.735 us; speedup 1.0000x reference)
//
#include <hip/hip_runtime.h>
#include <hip/hip_bf16.h>
#include <cstdint>
#include <cstddef>

#define DEVI __device__ __forceinline__

typedef short bf16x8 __attribute__((ext_vector_type(8)));
typedef float f32x4 __attribute__((ext_vector_type(4)));

DEVI ushort f2bf(float f) {
  union { float f; uint32_t u; } v; v.f = f;
  uint32_t u = v.u;
  uint32_t r = (u + 0x7FFFu + ((u >> 16) & 1u)) >> 16;  // RNE
  return (ushort)r;
}
DEVI float bf2f(ushort u) {
  union { uint32_t u; float f; } v; v.u = ((uint32_t)u) << 16;
  return v.f;
}
DEVI float sigmoidf_(float x) { return 1.f / (1.f + __expf(-x)); }
DEVI float tanhf_(float x) {
  float t = __expf(-2.f * fabsf(x));   // t in (0,1], no overflow
  float r = (1.f - t) / (1.f + t);
  return x >= 0.f ? r : -r;
}

DEVI void gload_lds16(const void* g, void* l) {
  __builtin_amdgcn_global_load_lds(
      (const __attribute__((address_space(1))) uint32_t*)g,
      (__attribute__((address_space(3))) uint32_t*)l, 16, 0, 0);
}

// ---------------- conversion kernels ----------------

__global__ void cvt_bf16_kernel(const float* __restrict__ src,
                                ushort* __restrict__ dst, int n4) {
  int i = blockIdx.x * blockDim.x + threadIdx.x;
  int stride = gridDim.x * blockDim.x;
  for (; i < n4; i += stride) {
    float4 v = ((const float4*)src)[i];
    ushort4 o;
    o.x = f2bf(v.x); o.y = f2bf(v.y); o.z = f2bf(v.z); o.w = f2bf(v.w);
    ((ushort4*)dst)[i] = o;
  }
}

// interleave 4 gate matrices [1024][1024] f32 -> [4096][1024] bf16
// row n = (j>>4)*64 + g*16 + (j&15)
__global__ void cvt_gates_kernel(const float* __restrict__ g0, const float* __restrict__ g1,
                                 const float* __restrict__ g2, const float* __restrict__ g3,
                                 ushort* __restrict__ dst) {
  int idx = blockIdx.x * 256 + threadIdx.x;  // 4096*256 exactly
  int n = idx >> 8;
  int k4 = idx & 255;
  int g = (n >> 4) & 3;
  int j = ((n >> 6) << 4) | (n & 15);
  const float* s = (g == 0 ? g0 : g == 1 ? g1 : g == 2 ? g2 : g3) + j * 1024 + k4 * 4;
  float4 v = *(const float4*)s;
  ushort4 o;
  o.x = f2bf(v.x); o.y = f2bf(v.y); o.z = f2bf(v.z); o.w = f2bf(v.w);
  ((ushort4*)(dst + (size_t)n * 1024))[k4] = o;
}

__global__ void init_kernel(const float* __restrict__ b0, const float* __restrict__ b1,
                            const float* __restrict__ b2, const float* __restrict__ b3,
                            float* __restrict__ br,
                            const float* __restrict__ h0, const float* __restrict__ c0,
                            ushort* __restrict__ hbf, float* __restrict__ cst) {
  int i = blockIdx.x * 256 + threadIdx.x;  // 262144 exactly
  if (i < 4096) {
    int g = (i >> 4) & 3;
    int j = ((i >> 6) << 4) | (i & 15);
    br[i] = (g == 0 ? b0 : g == 1 ? b1 : g == 2 ? b2 : b3)[j];
  }
  hbf[i] = f2bf(h0[i]);
  cst[i] = c0[i];
}

// ---------------- GEMM: C[m][n] = sum_k A[m][k]*B[n][k] + bias[n] ----------------
// 128x128 tile, BK=64, 4 waves (2x2 quadrants of 64x64), 16x16x32 bf16 MFMA.
// LDS tiles [128][64] bf16 with chunk-XOR swizzle (chunk ^= row&7), staged by
// global_load_lds w/ pre-swizzled per-lane source (linear LDS dest).
template <bool GATHER, bool OUT_BF16>
__global__ __launch_bounds__(256, 2) void gemm_bt_kernel(
    const ushort* __restrict__ A, const int* __restrict__ rowidx,
    const ushort* __restrict__ B, const float* __restrict__ bias,
    void* __restrict__ Cp, int Mt, int N, int K) {
  __shared__ __attribute__((aligned(16))) ushort lsA[128 * 64];
  __shared__ __attribute__((aligned(16))) ushort lsB[128 * 64];
  const int tid = threadIdx.x;
  const int w = tid >> 6, l = tid & 63;

  // bijective XCD swizzle
  int nwg = gridDim.x, bid = blockIdx.x;
  int q = nwg >> 3, r = nwg & 7;
  int xcd = bid & 7, lo = bid >> 3;
  int wg = (xcd < r ? xcd * (q + 1) : r * (q + 1) + (xcd - r) * q) + lo;
  const int bm = wg % Mt, bn = wg / Mt;
  const int m0 = bm * 128, n0 = bn * 128;

  // staging geometry: chunk c = i*256+tid; row=c>>3; stored col-chunk = c&7;
  // source col-chunk = (c&7) ^ (row&7)
  const int rowInB = tid >> 3;                              // 0..31
  const int ccByte = (((tid & 7) ^ (rowInB & 7)) << 4);     // swizzled source 16B chunk
  const char* aSrc[4];
  const char* bSrc[4];
#pragma unroll
  for (int i = 0; i < 4; ++i) {
    int row = i * 32 + rowInB;
    long arow = GATHER ? (long)rowidx[m0 + row] : (long)(m0 + row);
    aSrc[i] = (const char*)A + arow * (long)(K * 2) + ccByte;
    bSrc[i] = (const char*)B + (long)(n0 + row) * (long)(K * 2) + ccByte;
  }

  f32x4 acc[4][4] = {};
  const int wr = w >> 1, wc = w & 1;
  const int lrow = l & 15, lk = l >> 4;
  const int cbase = (lk ^ (l & 7)) << 4;  // swizzled read chunk (kk=0)
  uint32_t aOff[4], bOff[4];
#pragma unroll
  for (int f = 0; f < 4; ++f) {
    aOff[f] = (uint32_t)((wr * 64 + f * 16 + lrow) * 128 + cbase);
    bOff[f] = (uint32_t)((wc * 64 + f * 16 + lrow) * 128 + cbase);
  }

  const int kIters = K >> 6;
  for (int kt = 0; kt < kIters; ++kt) {
    const int kB = kt * 128;  // bytes along K
#pragma unroll
    for (int i = 0; i < 4; ++i) {
      gload_lds16(aSrc[i] + kB, (char*)lsA + i * 4096 + w * 1024);
      gload_lds16(bSrc[i] + kB, (char*)lsB + i * 4096 + w * 1024);
    }
    __syncthreads();
#pragma unroll
    for (int kk = 0; kk < 2; ++kk) {
      bf16x8 aF[4], bF[4];
#pragma unroll
      for (int f = 0; f < 4; ++f) {
        aF[f] = *(const bf16x8*)((const char*)lsA + (aOff[f] ^ (kk * 64)));
        bF[f] = *(const bf16x8*)((const char*)lsB + (bOff[f] ^ (kk * 64)));
      }
#pragma unroll
      for (int fm = 0; fm < 4; ++fm)
#pragma unroll
        for (int fn = 0; fn < 4; ++fn)
          acc[fm][fn] = __builtin_amdgcn_mfma_f32_16x16x32_bf16(aF[fm], bF[fn],
                                                                acc[fm][fn], 0, 0, 0);
    }
    __syncthreads();
  }

  // epilogue: C/D layout col=lane&15, row=(lane>>4)*4+reg
  const int mBase = m0 + wr * 64 + lk * 4;
  const int nBase = n0 + wc * 64 + lrow;
#pragma unroll
  for (int fn = 0; fn < 4; ++fn) {
    const int n = nBase + fn * 16;
    const float bv = bias[n];
#pragma unroll
    for (int fm = 0; fm < 4; ++fm) {
      const int m = mBase + fm * 16;
#pragma unroll
      for (int rr = 0; rr < 4; ++rr) {
        float v = acc[fm][fn][rr] + bv;
        if (OUT_BF16)
          ((ushort*)Cp)[(size_t)(m + rr) * N + n] = f2bf(v);
        else
          ((float*)Cp)[(size_t)(m + rr) * N + n] = v;
      }
    }
  }
}

// ---------------- fused LSTM step ----------------
// gates[b][n] = Apre[b][t][n] + sum_k h[b][k]*Vr[n][k]; block = 64 batch x 64 n
// (one jb group: 16 j x 4 gates); wave = 16 batch rows x 64 n -> lane-local cell update.
__global__ __launch_bounds__(256, 1) void lstm_step_kernel(
    const ushort* __restrict__ hprev, const ushort* __restrict__ Vr,
    const ushort* __restrict__ Apre, float* __restrict__ cst,
    ushort* __restrict__ hnext, int t) {
  __shared__ __attribute__((aligned(16))) ushort lsH[2][64 * 64];
  __shared__ __attribute__((aligned(16))) ushort lsV[2][64 * 64];
  const int tid = threadIdx.x;
  const int w = tid >> 6, l = tid & 63;
  int bid = blockIdx.x;
  int wg = (bid & 7) * 32 + (bid >> 3);  // 256 % 8 == 0, bijective
  const int bm = wg & 3, bn = wg >> 2;

  const int rowInB = tid >> 3;
  const int ccByte = (((tid & 7) ^ (rowInB & 7)) << 4);
  const char* hSrc[2];
  const char* vSrc[2];
#pragma unroll
  for (int i = 0; i < 2; ++i) {
    int row = i * 32 + rowInB;
    hSrc[i] = (const char*)hprev + (size_t)(bm * 64 + row) * 2048 + ccByte;
    vSrc[i] = (const char*)Vr + (size_t)(bn * 64 + row) * 2048 + ccByte;
  }
  const int lrow = l & 15, lk = l >> 4;
  const int cbase = (lk ^ (l & 7)) << 4;
  const uint32_t aOff = (uint32_t)((w * 16 + lrow) * 128 + cbase);
  uint32_t bOff[4];
#pragma unroll
  for (int f = 0; f < 4; ++f) bOff[f] = (uint32_t)((f * 16 + lrow) * 128 + cbase);

  f32x4 acc[4] = {};
  // prologue: stage kt=0
#pragma unroll
  for (int i = 0; i < 2; ++i) {
    gload_lds16(hSrc[i], (char*)lsH[0] + i * 4096 + w * 1024);
    gload_lds16(vSrc[i], (char*)lsV[0] + i * 4096 + w * 1024);
  }

  // Hoist tail operands: issue Apre + c loads NOW so their ~200-900 cyc
  // latency hides under the 16-iteration GEMM loop. Each (b_,j) cell is
  // owned by exactly one lane (race-free early read of cst).
  const int j = bn * 16 + lrow;
  float cold[4];
  ushort apv[4][4];
#pragma unroll
  for (int rr = 0; rr < 4; ++rr) {
    const int b_ = bm * 64 + w * 16 + lk * 4 + rr;
    const ushort* ap = Apre + ((size_t)b_ * 128 + t) * 4096 + bn * 64 + lrow;
    apv[rr][0] = ap[0];
    apv[rr][1] = ap[16];
    apv[rr][2] = ap[32];
    apv[rr][3] = ap[48];
    cold[rr] = cst[b_ * 1024 + j];
  }

  __syncthreads();
  for (int kt = 0; kt < 16; ++kt) {
    const int cur = kt & 1;
    if (kt < 15) {  // prefetch next k-tile into other buffer (overlaps compute)
      const int kB = (kt + 1) * 128;
#pragma unroll
      for (int i = 0; i < 2; ++i) {
        gload_lds16(hSrc[i] + kB, (char*)lsH[cur ^ 1] + i * 4096 + w * 1024);
        gload_lds16(vSrc[i] + kB, (char*)lsV[cur ^ 1] + i * 4096 + w * 1024);
      }
    }
#pragma unroll
    for (int kk = 0; kk < 2; ++kk) {
      bf16x8 aF = *(const bf16x8*)((const char*)lsH[cur] + (aOff ^ (kk * 64)));
#pragma unroll
      for (int f = 0; f < 4; ++f) {
        bf16x8 bF = *(const bf16x8*)((const char*)lsV[cur] + (bOff[f] ^ (kk * 64)));
        acc[f] = __builtin_amdgcn_mfma_f32_16x16x32_bf16(aF, bF, acc[f], 0, 0, 0);
      }
    }
    __syncthreads();
  }

  // cell update: fn index == gate (0=i,1=f,2=g,3=o); j = bn*16 + (lane&15)
#pragma unroll
  for (int rr = 0; rr < 4; ++rr) {
    const int b_ = bm * 64 + w * 16 + lk * 4 + rr;
    float ip = acc[0][rr] + bf2f(apv[rr][0]);
    float fp = acc[1][rr] + bf2f(apv[rr][1]);
    float gp = acc[2][rr] + bf2f(apv[rr][2]);
    float op = acc[3][rr] + bf2f(apv[rr][3]);
    float iv = sigmoidf_(ip), fv = sigmoidf_(fp), gv = tanhf_(gp), ov = sigmoidf_(op);
    const int ci = b_ * 1024 + j;
    float cv = fv * cold[rr] + iv * gv;
    cst[ci] = cv;
    hnext[ci] = f2bf(ov * tanhf_(cv));
  }
}

// ---------------- launch ----------------

extern "C" void kernel_launch(void* const* d_in, const int* in_sizes, int n_in,
                              void* d_out, int out_size, void* d_ws, size_t ws_size,
                              hipStream_t stream) {
  const int* X = (const int*)d_in[0];
  const float* h0 = (const float*)d_in[1];
  const float* c0 = (const float*)d_in[2];
  const float* emb = (const float*)d_in[3];
  const float* U0 = (const float*)d_in[4];
  const float* V0 = (const float*)d_in[5];
  const float* b0 = (const float*)d_in[6];
  const float* U1 = (const float*)d_in[7];
  const float* V1 = (const float*)d_in[8];
  const float* b1 = (const float*)d_in[9];
  const float* U2 = (const float*)d_in[10];
  const float* V2 = (const float*)d_in[11];
  const float* b2 = (const float*)d_in[12];
  const float* U3 = (const float*)d_in[13];
  const float* V3 = (const float*)d_in[14];
  const float* b3 = (const float*)d_in[15];
  const float* W = (const float*)d_in[16];
  const float* bfin = (const float*)d_in[17];

  // Workspace layout (336.5 MiB total). embbf and Wbf OVERLAY each other:
  // emb (bf16) is dead after the input GEMM; W (bf16) is created after it.
  char* ws = (char*)d_ws;
  ushort* embWbf = (ushort*)(ws);                 // 65,536,000 B (emb, then W)
  ushort* Ur    = (ushort*)(ws + 65536000);       //  8,388,608 B
  ushort* Vr    = (ushort*)(ws + 73924608);       //  8,388,608 B
  float*  br    = (float*)(ws + 82313216);        //     16,384 B
  ushort* Apre  = (ushort*)(ws + 82329600);       // 268,435,456 B
  ushort* hA    = (ushort*)(ws + 350765056);      //    524,288 B
  ushort* hB    = (ushort*)(ws + 351289344);      //    524,288 B
  float*  cst   = (float*)(ws + 351813632);       //  1,048,576 B

  cvt_bf16_kernel<<<4096, 256, 0, stream>>>(emb, embWbf, 32768000 / 4);
  cvt_gates_kernel<<<4096, 256, 0, stream>>>(U0, U1, U2, U3, Ur);
  cvt_gates_kernel<<<4096, 256, 0, stream>>>(V0, V1, V2, V3, Vr);
  init_kernel<<<1024, 256, 0, stream>>>(b0, b1, b2, b3, br, h0, c0, hA, cst);

  // Apre[(b*128+t)][n] = emb[X] @ Ur^T + br   (M=32768, N=4096, K=1024)
  gemm_bt_kernel<true, true><<<8192, 256, 0, stream>>>(embWbf, X, Ur, br, Apre,
                                                       256, 4096, 1024);

  // emb no longer needed; convert W into the same region (stream-ordered).
  cvt_bf16_kernel<<<4096, 256, 0, stream>>>(W, embWbf, 32768000 / 4);

  ushort* hb[2] = {hA, hB};
  for (int t = 0; t < 128; ++t)
    lstm_step_kernel<<<256, 256, 0, stream>>>(hb[t & 1], Vr, Apre, cst,
                                              hb[(t + 1) & 1], t);

  // out = h @ W^T + b   (M=256, N=32000, K=1024), final h is in hA
  gemm_bt_kernel<false, false><<<500, 256, 0, stream>>>(hA, nullptr, embWbf, bfin,
                                                        (float*)d_out, 2, 32000, 1024);
}